// Round 19
// baseline (5419.753 us; speedup 1.0000x reference)
//
#include <hip/hip_runtime.h>

#define T_STEPS 512
#define BATCH   64
#define HID     512
#define SENT32  0x7F807F80u
#define SENT64  0x7F807F807F807F80ull

typedef __attribute__((ext_vector_type(8))) short short8;
typedef __attribute__((ext_vector_type(4))) float f32x4;
typedef __attribute__((ext_vector_type(4))) int   int4v;

__device__ __forceinline__ unsigned short f2bf(float f){
  unsigned u = __float_as_uint(f);
  u += 0x7FFF + ((u >> 16) & 1);           // RNE
  return (unsigned short)(u >> 16);
}
__device__ __forceinline__ float bf2f(unsigned short s){
  return __uint_as_float(((unsigned)s) << 16);
}
__device__ __forceinline__ f32x4 mfma16(short8 a, short8 b, f32x4 c){
  return __builtin_amdgcn_mfma_f32_16x16x32_bf16(a, b, c, 0, 0, 0);
}
__device__ __forceinline__ float sigf(float x){
  return 1.0f / (1.0f + exp2f(-1.44269504f * x));
}
__device__ __forceinline__ float tanh_(float x){
  float e = exp2f(2.88539008f * x);
  return 1.0f - 2.0f / (1.0f + e);
}

// ---- hot all-wave spin (R8/R16, unchanged) ----
__device__ __forceinline__ void spinL0(int* flags0, int target){
  int lane = threadIdx.x & 63;
  int* p = &flags0[(lane & 31)*32];
  float a0 = 1.0f;
  int guard = 0;
  for (;;){
    int v = __hip_atomic_load(p, __ATOMIC_RELAXED, __HIP_MEMORY_SCOPE_AGENT);
    if (__ballot(v >= target) == ~0ull) break;
    #pragma unroll
    for (int i = 0; i < 8; ++i) a0 = __builtin_fmaf(a0, 1.000001f, 0.000001f);
    if (++guard > (1 << 18)) break;      // anti-hang safety
  }
  asm volatile("" :: "v"(a0));
  asm volatile("" ::: "memory");
  __builtin_amdgcn_fence(__ATOMIC_ACQUIRE, "workgroup");
}

__device__ __forceinline__ void spinL1(int* flags0, int* flags1, int t){
  int lane = threadIdx.x & 63;
  int* p   = (lane < 32) ? &flags0[lane*32] : &flags1[(lane-32)*32];
  int tgt  = (lane < 32) ? t + 1 : t;
  float a0 = 1.0f;
  int guard = 0;
  for (;;){
    int v = __hip_atomic_load(p, __ATOMIC_RELAXED, __HIP_MEMORY_SCOPE_AGENT);
    if (__ballot(v >= tgt) == ~0ull) break;
    #pragma unroll
    for (int i = 0; i < 8; ++i) a0 = __builtin_fmaf(a0, 1.000001f, 0.000001f);
    if (++guard > (1 << 18)) break;
  }
  asm volatile("" :: "v"(a0));
  asm volatile("" ::: "memory");
  __builtin_amdgcn_fence(__ATOMIC_ACQUIRE, "workgroup");
}

__device__ __forceinline__ void signalSlot(int* slot, int val){
  __builtin_amdgcn_fence(__ATOMIC_RELEASE, "workgroup");
  asm volatile("" ::: "memory");
  __hip_atomic_store(slot, val, __ATOMIC_RELAXED, __HIP_MEMORY_SCOPE_AGENT);
}

// Weight fragments: layout [tau][16 rows][K] bf16, K-contiguous.
template<int NKB>
__device__ __forceinline__ void loadB(const unsigned short* __restrict__ Wg, int K, int kstart,
                                      int l15, int l4, short8 B[4][NKB]){
  #pragma unroll
  for (int tt = 0; tt < 4; ++tt)
    #pragma unroll
    for (int kb = 0; kb < NKB; ++kb)
      B[tt][kb] = *(const short8*)(Wg + (long)(tt*16 + l15)*K + kstart + kb*32 + l4*8);
}

// acc[m][tau] += W[tau] * A[m]^T  (swapped operands: D col=batch, row=gate)
template<int NKB>
__device__ __forceinline__ void gemmA(const unsigned short* __restrict__ Ab, long rs,
                                      int l15, int l4, const short8 B[4][NKB], f32x4 acc[4][4]){
  #pragma unroll
  for (int kb = 0; kb < NKB; ++kb){
    short8 a[4];
    #pragma unroll
    for (int m = 0; m < 4; ++m)
      a[m] = *(const short8*)(Ab + (long)(m*16 + l15)*rs + kb*32 + l4*8);
    #pragma unroll
    for (int m = 0; m < 4; ++m)
      #pragma unroll
      for (int tt = 0; tt < 4; ++tt)
        acc[m][tt] = mfma16(B[tt][kb], a[m], acc[m][tt]);
  }
}

// Flag-gated batched load with sentinel verification: one asm block, all 32
// 16B loads sc0 sc1 (coherence-point), single vmcnt. Flag may RACE the data
// stores (producer no longer drains) -> verify every dword != bf16-inf
// sentinel; rare retry refetches. Common case: 1 iteration.
__device__ __forceinline__ void pollLoadA8(const unsigned short* __restrict__ Ab, long rs,
                                           int l15, int l4, short8 a[4][8]){
  const unsigned short* p0 = Ab + (long)(     l15)*rs + l4*8;
  const unsigned short* p1 = Ab + (long)(16 + l15)*rs + l4*8;
  const unsigned short* p2 = Ab + (long)(32 + l15)*rs + l4*8;
  const unsigned short* p3 = Ab + (long)(48 + l15)*rs + l4*8;
  int4v v[32];
  int guard = 0;
  for (;;){
    asm volatile(
      "global_load_dwordx4 %0, %32, off sc0 sc1\n\t"
      "global_load_dwordx4 %1, %32, off offset:64 sc0 sc1\n\t"
      "global_load_dwordx4 %2, %32, off offset:128 sc0 sc1\n\t"
      "global_load_dwordx4 %3, %32, off offset:192 sc0 sc1\n\t"
      "global_load_dwordx4 %4, %32, off offset:256 sc0 sc1\n\t"
      "global_load_dwordx4 %5, %32, off offset:320 sc0 sc1\n\t"
      "global_load_dwordx4 %6, %32, off offset:384 sc0 sc1\n\t"
      "global_load_dwordx4 %7, %32, off offset:448 sc0 sc1\n\t"
      "global_load_dwordx4 %8, %33, off sc0 sc1\n\t"
      "global_load_dwordx4 %9, %33, off offset:64 sc0 sc1\n\t"
      "global_load_dwordx4 %10, %33, off offset:128 sc0 sc1\n\t"
      "global_load_dwordx4 %11, %33, off offset:192 sc0 sc1\n\t"
      "global_load_dwordx4 %12, %33, off offset:256 sc0 sc1\n\t"
      "global_load_dwordx4 %13, %33, off offset:320 sc0 sc1\n\t"
      "global_load_dwordx4 %14, %33, off offset:384 sc0 sc1\n\t"
      "global_load_dwordx4 %15, %33, off offset:448 sc0 sc1\n\t"
      "global_load_dwordx4 %16, %34, off sc0 sc1\n\t"
      "global_load_dwordx4 %17, %34, off offset:64 sc0 sc1\n\t"
      "global_load_dwordx4 %18, %34, off offset:128 sc0 sc1\n\t"
      "global_load_dwordx4 %19, %34, off offset:192 sc0 sc1\n\t"
      "global_load_dwordx4 %20, %34, off offset:256 sc0 sc1\n\t"
      "global_load_dwordx4 %21, %34, off offset:320 sc0 sc1\n\t"
      "global_load_dwordx4 %22, %34, off offset:384 sc0 sc1\n\t"
      "global_load_dwordx4 %23, %34, off offset:448 sc0 sc1\n\t"
      "global_load_dwordx4 %24, %35, off sc0 sc1\n\t"
      "global_load_dwordx4 %25, %35, off offset:64 sc0 sc1\n\t"
      "global_load_dwordx4 %26, %35, off offset:128 sc0 sc1\n\t"
      "global_load_dwordx4 %27, %35, off offset:192 sc0 sc1\n\t"
      "global_load_dwordx4 %28, %35, off offset:256 sc0 sc1\n\t"
      "global_load_dwordx4 %29, %35, off offset:320 sc0 sc1\n\t"
      "global_load_dwordx4 %30, %35, off offset:384 sc0 sc1\n\t"
      "global_load_dwordx4 %31, %35, off offset:448 sc0 sc1\n\t"
      "s_waitcnt vmcnt(0)"
      : "=&v"(v[0]),  "=&v"(v[1]),  "=&v"(v[2]),  "=&v"(v[3]),
        "=&v"(v[4]),  "=&v"(v[5]),  "=&v"(v[6]),  "=&v"(v[7]),
        "=&v"(v[8]),  "=&v"(v[9]),  "=&v"(v[10]), "=&v"(v[11]),
        "=&v"(v[12]), "=&v"(v[13]), "=&v"(v[14]), "=&v"(v[15]),
        "=&v"(v[16]), "=&v"(v[17]), "=&v"(v[18]), "=&v"(v[19]),
        "=&v"(v[20]), "=&v"(v[21]), "=&v"(v[22]), "=&v"(v[23]),
        "=&v"(v[24]), "=&v"(v[25]), "=&v"(v[26]), "=&v"(v[27]),
        "=&v"(v[28]), "=&v"(v[29]), "=&v"(v[30]), "=&v"(v[31])
      : "v"(p0), "v"(p1), "v"(p2), "v"(p3)
      : "memory");
    bool ok = true;
    #pragma unroll
    for (int i = 0; i < 32; ++i){
      ok = ok && (unsigned(v[i][0]) != SENT32) && (unsigned(v[i][1]) != SENT32)
              && (unsigned(v[i][2]) != SENT32) && (unsigned(v[i][3]) != SENT32);
    }
    if (__ballot(ok) == ~0ull) break;
    if (++guard > (1 << 17)) break;      // anti-hang safety
  }
  #pragma unroll
  for (int m = 0; m < 4; ++m)
    #pragma unroll
    for (int kb = 0; kb < 8; ++kb)
      a[m][kb] = *(short8*)&v[m*8 + kb];
}

template<int NKB>
__device__ __forceinline__ void mfmaA(const short8 a[4][NKB], const short8 B[4][NKB],
                                      f32x4 acc[4][4]){
  #pragma unroll
  for (int kb = 0; kb < NKB; ++kb)
    #pragma unroll
    for (int m = 0; m < 4; ++m)
      #pragma unroll
      for (int tt = 0; tt < 4; ++tt)
        acc[m][tt] = mfma16(B[tt][kb], a[m][kb], acc[m][tt]);
}

// All-to-all K-partial reduce through LDS. Wave w finalizes batch-tile m==w.
__device__ __forceinline__ void reduceWrite(float* red, int w, int l15, int l4, f32x4 acc[4][4]){
  #pragma unroll
  for (int m = 0; m < 4; ++m){
    if (m == w) continue;
    int mi = (m > w) ? m - 1 : m;
    #pragma unroll
    for (int tt = 0; tt < 4; ++tt){
      float* p = red + (w*12 + mi*4 + tt)*320 + l15*20 + l4*4;
      *(f32x4*)p = acc[m][tt];
    }
  }
}
__device__ __forceinline__ void reduceRead(const float* red, int w, int l15, int l4,
                                           f32x4 gf[4], f32x4 acc[4][4]){
  #pragma unroll
  for (int tt = 0; tt < 4; ++tt) gf[tt] = acc[w][tt];
  #pragma unroll
  for (int v = 0; v < 4; ++v){
    if (v == w) continue;
    int mi = (w > v) ? w - 1 : w;
    #pragma unroll
    for (int tt = 0; tt < 4; ++tt){
      const float* p = red + (v*12 + mi*4 + tt)*320 + l15*20 + l4*4;
      gf[tt] += *(const f32x4*)p;
    }
  }
}

// Gate math + packed 8B agent-coherent h store (fire-and-forget; sentinel-verified
// by consumers).
__device__ __forceinline__ void gatesStore(f32x4 gf[4], f32x4& cst,
                                           unsigned short* __restrict__ hdst){
  f32x4 hh;
  #pragma unroll
  for (int r = 0; r < 4; ++r){
    float iv = sigf(gf[0][r]), fv = sigf(gf[1][r]);
    float gv = tanh_(gf[2][r]), ov = sigf(gf[3][r]);
    float cv = fv * cst[r] + iv * gv;
    cst[r] = cv;
    hh[r] = ov * tanh_(cv);
  }
  unsigned long long pk = (unsigned long long)f2bf(hh[0])
    | ((unsigned long long)f2bf(hh[1]) << 16)
    | ((unsigned long long)f2bf(hh[2]) << 32)
    | ((unsigned long long)f2bf(hh[3]) << 48);
  __hip_atomic_store((unsigned long long*)hdst, pk, __ATOMIC_RELAXED, __HIP_MEMORY_SCOPE_AGENT);
}

// ---------------- layer 0 recurrent (R8, unchanged; drained flag protocol) ----------------
template<int NXB, int NHB>
__device__ void l0_loop(int g, int w, int lane,
                        const unsigned short* __restrict__ Wg,
                        const float* __restrict__ bias0,
                        const unsigned short* __restrict__ xb,
                        unsigned short* __restrict__ h0seq,
                        int* flags0, float* red, int hk0){
  int l15 = lane & 15, l4 = lane >> 4;
  short8 Bx[4][(NXB > 0) ? NXB : 1];
  if constexpr (NXB > 0) loadB<NXB>(Wg, 576, 0, l15, l4, Bx);
  short8 Bh[4][NHB];
  loadB<NHB>(Wg, 576, 64 + hk0, l15, l4, Bh);
  f32x4 bsv[4];
  #pragma unroll
  for (int tt = 0; tt < 4; ++tt) bsv[tt] = *(const f32x4*)&bias0[(g*4 + tt)*16 + l4*4];
  f32x4 cst = {0.f, 0.f, 0.f, 0.f};
  int b = w*16 + l15, colb = g*16 + l4*4;

  for (int t = 0; t < T_STEPS; ++t){
    f32x4 acc[4][4];
    #pragma unroll
    for (int m = 0; m < 4; ++m)
      #pragma unroll
      for (int tt = 0; tt < 4; ++tt) acc[m][tt] = (f32x4){0.f,0.f,0.f,0.f};
    if constexpr (NXB > 0)
      gemmA<NXB>(xb + (long)t*64, (long)T_STEPS*64, l15, l4, Bx, acc);
    if (t){
      spinL0(flags0, t);
      gemmA<NHB>(h0seq + (long)(t-1)*BATCH*HID + hk0, HID, l15, l4, Bh, acc);
    }
    reduceWrite(red, w, l15, l4, acc);
    __syncthreads();
    f32x4 gf[4];
    reduceRead(red, w, l15, l4, gf, acc);
    #pragma unroll
    for (int tt = 0; tt < 4; ++tt) gf[tt] += bsv[tt];
    gatesStore(gf, cst, h0seq + (long)t*BATCH*HID + (long)b*HID + colb);
    __syncthreads();                      // L0 keeps drained protocol (off-critical)
    if (threadIdx.x == 0) signalSlot(&flags0[g*32], t + 1);
  }
}

// ---- layer 1: flag-gated + sentinel-verified loads; NO producer store drain ----
__device__ void l1_loop(int g, int w, int lane,
                        const unsigned short* __restrict__ Wg,
                        const float* __restrict__ bias1,
                        const unsigned short* __restrict__ h0seq,
                        unsigned short* __restrict__ h1seq,
                        int* flags0, int* flags1, float* red){
  int l15 = lane & 15, l4 = lane >> 4;
  short8 Bh[4][8];
  loadB<8>(Wg, 1024, w*256, l15, l4, Bh);
  f32x4 bsv[4];
  #pragma unroll
  for (int tt = 0; tt < 4; ++tt) bsv[tt] = *(const f32x4*)&bias1[(g*4 + tt)*16 + l4*4];
  f32x4 cst = {0.f, 0.f, 0.f, 0.f};
  int b = w*16 + l15, colb = g*16 + l4*4;

  for (int t = 0; t < T_STEPS; ++t){
    spinL1(flags0, flags1, t);
    f32x4 acc[4][4];
    #pragma unroll
    for (int m = 0; m < 4; ++m)
      #pragma unroll
      for (int tt = 0; tt < 4; ++tt) acc[m][tt] = (f32x4){0.f,0.f,0.f,0.f};
    if (w < 2){
      short8 ah[4][8];
      pollLoadA8(h0seq + (long)t*BATCH*HID + w*256, HID, l15, l4, ah);
      mfmaA<8>(ah, Bh, acc);
    } else if (t){
      short8 ah[4][8];
      pollLoadA8(h1seq + (long)(t-1)*BATCH*HID + (w-2)*256, HID, l15, l4, ah);
      mfmaA<8>(ah, Bh, acc);
    }
    reduceWrite(red, w, l15, l4, acc);
    __syncthreads();
    f32x4 gf[4];
    reduceRead(red, w, l15, l4, gf, acc);
    #pragma unroll
    for (int tt = 0; tt < 4; ++tt) gf[tt] += bsv[tt];
    gatesStore(gf, cst, h1seq + (long)t*BATCH*HID + (long)b*HID + colb);
    // raw LDS-only barrier: rendezvous for red reuse WITHOUT vmem drain —
    // the h-store races the flag; consumers sentinel-verify.
    asm volatile("s_waitcnt lgkmcnt(0)\n\ts_barrier" ::: "memory");
    if (threadIdx.x == 0) signalSlot(&flags1[g*32], t + 1);
  }
}

// ---------------- persistent kernel ----------------
extern "C" __global__ void __launch_bounds__(256, 1)
lstm_persist(const unsigned short* __restrict__ Wpk0,
             const unsigned short* __restrict__ Wpk1,
             const float* __restrict__ bias0, const float* __restrict__ bias1,
             const unsigned short* __restrict__ xb,
             unsigned short* __restrict__ h0seq, unsigned short* __restrict__ h1seq,
             int* flags0, int* flags1){
  __shared__ float red[15360];   // 60 KB reduce buffer
  int wg = blockIdx.x;
  int role = wg >> 5;
  int g = wg & 31;
  int w = threadIdx.x >> 6;
  int lane = threadIdx.x & 63;

  if (role == 0){
    const unsigned short* Wg = Wpk0 + (long)g*4*16*576;
    switch (w){
      case 0:  l0_loop<2,3>(g, 0, lane, Wg, bias0, xb, h0seq, flags0, red, 0);   break;
      case 1:  l0_loop<0,5>(g, 1, lane, Wg, bias0, xb, h0seq, flags0, red, 96);  break;
      case 2:  l0_loop<0,4>(g, 2, lane, Wg, bias0, xb, h0seq, flags0, red, 256); break;
      default: l0_loop<0,4>(g, 3, lane, Wg, bias0, xb, h0seq, flags0, red, 384); break;
    }
  } else {
    const unsigned short* Wg = Wpk1 + (long)g*4*16*1024;
    l1_loop(g, w, lane, Wg, bias1, h0seq, h1seq, flags0, flags1, red);
  }
}

// ---------------- prep: repack weights, convert x, poison h, zero flags ----------------
extern "C" __global__ void prep_kernel(const float* __restrict__ x,
    const float* __restrict__ Wih0, const float* __restrict__ Whh0,
    const float* __restrict__ bih0, const float* __restrict__ bhh0,
    const float* __restrict__ Wih1, const float* __restrict__ Whh1,
    const float* __restrict__ bih1, const float* __restrict__ bhh1,
    unsigned short* __restrict__ Wpk0, unsigned short* __restrict__ Wpk1,
    float* __restrict__ bias0, float* __restrict__ bias1,
    unsigned short* __restrict__ xb, int* __restrict__ syncm,
    unsigned long long* __restrict__ h0p, unsigned long long* __restrict__ h1p){
  long gid = (long)blockIdx.x * blockDim.x + threadIdx.x;
  long gs  = (long)gridDim.x * blockDim.x;
  const long NW0 = 32L*4*16*576;
  const long NW1 = 32L*4*16*1024;
  const long NX  = 64L*512*64;
  const long NH8 = (long)T_STEPS*BATCH*HID/4;   // u64 count per h buffer

  for (long i = gid; i < NW0; i += gs){
    int k = (int)(i % 576);
    long q = i / 576;
    int r  = (int)(q & 15);
    long q2 = q >> 4;
    int tt = (int)(q2 & 3);
    int g  = (int)(q2 >> 2);
    int row = tt*512 + g*16 + r;
    float v = (k < 64) ? Wih0[(long)row*64 + k] : Whh0[(long)row*512 + (k - 64)];
    Wpk0[i] = f2bf(v);
  }
  for (long i = gid; i < NW1; i += gs){
    int k = (int)(i & 1023);
    long q = i >> 10;
    int r  = (int)(q & 15);
    long q2 = q >> 4;
    int tt = (int)(q2 & 3);
    int g  = (int)(q2 >> 2);
    int row = tt*512 + g*16 + r;
    float v = (k < 512) ? Wih1[(long)row*512 + k] : Whh1[(long)row*512 + (k - 512)];
    Wpk1[i] = f2bf(v);
  }
  for (long i = gid; i < 2048; i += gs){
    int r = (int)(i & 15);
    int tt = (int)((i >> 4) & 3);
    int g  = (int)(i >> 6);
    int row = tt*512 + g*16 + r;
    bias0[i] = bih0[row] + bhh0[row];
    bias1[i] = bih1[row] + bhh1[row];
  }
  for (long i = gid; i < NX; i += gs) xb[i] = f2bf(x[i]);
  for (long i = gid; i < 2048; i += gs) syncm[i] = 0;   // flags0 + flags1
  for (long i = gid; i < NH8; i += gs){ h0p[i] = SENT64; h1p[i] = SENT64; }
}

// ---------------- head: out[b,t] = h1[t,b,:] . wfc + bfc ----------------
extern "C" __global__ void head_kernel(const unsigned short* __restrict__ h1seq,
    const float* __restrict__ wfc, const float* __restrict__ bfc,
    float* __restrict__ out){
  int t = blockIdx.x;
  int tid = threadIdx.x;
  int b = tid >> 2, q = tid & 3;
  const unsigned short* hp = h1seq + ((long)t*BATCH + b)*HID + q*128;
  const float* wp = wfc + q*128;
  float s = 0.f;
  #pragma unroll
  for (int i = 0; i < 16; ++i){
    short8 v = *(const short8*)(hp + i*8);
    #pragma unroll
    for (int e = 0; e < 8; ++e)
      s += bf2f((unsigned short)v[e]) * wp[i*8 + e];
  }
  s += __shfl_xor(s, 1, 64);
  s += __shfl_xor(s, 2, 64);
  if (q == 0) out[(long)b*T_STEPS + t] = s + bfc[0];
}

extern "C" void kernel_launch(void* const* d_in, const int* in_sizes, int n_in,
                              void* d_out, int out_size, void* d_ws, size_t ws_size,
                              hipStream_t stream){
  const float* x    = (const float*)d_in[0];
  const float* Wih0 = (const float*)d_in[1];
  const float* Whh0 = (const float*)d_in[2];
  const float* bih0 = (const float*)d_in[3];
  const float* bhh0 = (const float*)d_in[4];
  const float* Wih1 = (const float*)d_in[5];
  const float* Whh1 = (const float*)d_in[6];
  const float* bih1 = (const float*)d_in[7];
  const float* bhh1 = (const float*)d_in[8];
  const float* wfc  = (const float*)d_in[9];
  const float* bfc  = (const float*)d_in[10];
  float* out = (float*)d_out;

  char* p = (char*)d_ws;
  auto carve = [&](size_t bytes) -> void* {
    void* r = (void*)p;
    p += (bytes + 255) & ~(size_t)255;
    return r;
  };
  unsigned short* Wpk0  = (unsigned short*)carve(32L*4*16*576*2);
  unsigned short* Wpk1  = (unsigned short*)carve(32L*4*16*1024*2);
  float* bias0 = (float*)carve(2048*4);
  float* bias1 = (float*)carve(2048*4);
  unsigned short* xb    = (unsigned short*)carve(64L*512*64*2);
  unsigned short* h0seq = (unsigned short*)carve(512L*64*512*2);
  unsigned short* h1seq = (unsigned short*)carve(512L*64*512*2);
  int* syncm   = (int*)carve(8192);
  int* flags0 = syncm;           // 32 slots x 32-int stride (128B lines)
  int* flags1 = syncm + 1024;

  hipLaunchKernelGGL(prep_kernel, dim3(1024), dim3(256), 0, stream,
                     x, Wih0, Whh0, bih0, bhh0, Wih1, Whh1, bih1, bhh1,
                     Wpk0, Wpk1, bias0, bias1, xb, syncm,
                     (unsigned long long*)h0seq, (unsigned long long*)h1seq);
  hipLaunchKernelGGL(lstm_persist, dim3(64), dim3(256), 0, stream,
                     Wpk0, Wpk1, bias0, bias1, xb, h0seq, h1seq, flags0, flags1);
  hipLaunchKernelGGL(head_kernel, dim3(512), dim3(256), 0, stream,
                     h1seq, wfc, bfc, out);
}

// Round 20
// 4698.624 us; speedup vs baseline: 1.1535x; 1.1535x over previous
//
#include <hip/hip_runtime.h>

#define T_STEPS 512
#define BATCH   64
#define HID     512

typedef __attribute__((ext_vector_type(8))) short short8;
typedef __attribute__((ext_vector_type(4))) float f32x4;

__device__ __forceinline__ unsigned short f2bf(float f){
  unsigned u = __float_as_uint(f);
  u += 0x7FFF + ((u >> 16) & 1);           // RNE
  return (unsigned short)(u >> 16);
}
__device__ __forceinline__ float bf2f(unsigned short s){
  return __uint_as_float(((unsigned)s) << 16);
}
__device__ __forceinline__ f32x4 mfma16(short8 a, short8 b, f32x4 c){
  return __builtin_amdgcn_mfma_f32_16x16x32_bf16(a, b, c, 0, 0, 0);
}
__device__ __forceinline__ float sigf(float x){
  return 1.0f / (1.0f + exp2f(-1.44269504f * x));
}
__device__ __forceinline__ float tanh_(float x){
  float e = exp2f(2.88539008f * x);
  return 1.0f - 2.0f / (1.0f + e);
}

// ---- hot all-wave spin ----
__device__ __forceinline__ void spinL0(int* flags0, int target){
  int lane = threadIdx.x & 63;
  int* p = &flags0[(lane & 31)*32];
  float a0 = 1.0f;
  int guard = 0;
  for (;;){
    int v = __hip_atomic_load(p, __ATOMIC_RELAXED, __HIP_MEMORY_SCOPE_AGENT);
    if (__ballot(v >= target) == ~0ull) break;
    #pragma unroll
    for (int i = 0; i < 8; ++i) a0 = __builtin_fmaf(a0, 1.000001f, 0.000001f);
    if (++guard > (1 << 18)) break;      // anti-hang safety
  }
  asm volatile("" :: "v"(a0));           // keep filler alive (no DCE)
  asm volatile("" ::: "memory");
  __builtin_amdgcn_fence(__ATOMIC_ACQUIRE, "workgroup");  // compiler ordering
}

__device__ __forceinline__ void spinL1(int* flags0, int* flags1, int t){
  int lane = threadIdx.x & 63;
  int* p   = (lane < 32) ? &flags0[lane*32] : &flags1[(lane-32)*32];
  int tgt  = (lane < 32) ? t + 1 : t;
  float a0 = 1.0f;
  int guard = 0;
  for (;;){
    int v = __hip_atomic_load(p, __ATOMIC_RELAXED, __HIP_MEMORY_SCOPE_AGENT);
    if (__ballot(v >= tgt) == ~0ull) break;
    #pragma unroll
    for (int i = 0; i < 8; ++i) a0 = __builtin_fmaf(a0, 1.000001f, 0.000001f);
    if (++guard > (1 << 18)) break;
  }
  asm volatile("" :: "v"(a0));
  asm volatile("" ::: "memory");
  __builtin_amdgcn_fence(__ATOMIC_ACQUIRE, "workgroup");
}

// Call AFTER __syncthreads() (which drains all waves' sc1 stores): publish step.
__device__ __forceinline__ void signalSlot(int* slot, int val){
  __builtin_amdgcn_fence(__ATOMIC_RELEASE, "workgroup");  // compiler ordering
  asm volatile("" ::: "memory");
  __hip_atomic_store(slot, val, __ATOMIC_RELAXED, __HIP_MEMORY_SCOPE_AGENT);
}

// Weight fragments: layout [tau][16 rows][K] bf16, K-contiguous.
template<int NKB>
__device__ __forceinline__ void loadB(const unsigned short* __restrict__ Wg, int K, int kstart,
                                      int l15, int l4, short8 B[4][NKB]){
  #pragma unroll
  for (int tt = 0; tt < 4; ++tt)
    #pragma unroll
    for (int kb = 0; kb < NKB; ++kb)
      B[tt][kb] = *(const short8*)(Wg + (long)(tt*16 + l15)*K + kstart + kb*32 + l4*8);
}

// acc[m][tau] += W[tau] * A[m]^T  (swapped operands: D col=batch, row=gate)
template<int NKB>
__device__ __forceinline__ void gemmA(const unsigned short* __restrict__ Ab, long rs,
                                      int l15, int l4, const short8 B[4][NKB], f32x4 acc[4][4]){
  #pragma unroll
  for (int kb = 0; kb < NKB; ++kb){
    short8 a[4];
    #pragma unroll
    for (int m = 0; m < 4; ++m)
      a[m] = *(const short8*)(Ab + (long)(m*16 + l15)*rs + kb*32 + l4*8);
    #pragma unroll
    for (int m = 0; m < 4; ++m)
      #pragma unroll
      for (int tt = 0; tt < 4; ++tt)
        acc[m][tt] = mfma16(B[tt][kb], a[m], acc[m][tt]);
  }
}

// FORCED-batch A load: all 32 16B loads issued back-to-back in ONE asm block,
// single vmcnt(0) -> one LLC round trip instead of 8 serial ones. Outputs are
// asm register tuples; MFMAs data-depend on them (no hoisting hazard).
__device__ __forceinline__ void loadA8(const unsigned short* __restrict__ Ab, long rs,
                                       int l15, int l4, short8 a[4][8]){
  const unsigned short* p0 = Ab + (long)(     l15)*rs + l4*8;
  const unsigned short* p1 = Ab + (long)(16 + l15)*rs + l4*8;
  const unsigned short* p2 = Ab + (long)(32 + l15)*rs + l4*8;
  const unsigned short* p3 = Ab + (long)(48 + l15)*rs + l4*8;
  asm volatile(
    "global_load_dwordx4 %0, %32, off\n\t"
    "global_load_dwordx4 %1, %32, off offset:64\n\t"
    "global_load_dwordx4 %2, %32, off offset:128\n\t"
    "global_load_dwordx4 %3, %32, off offset:192\n\t"
    "global_load_dwordx4 %4, %32, off offset:256\n\t"
    "global_load_dwordx4 %5, %32, off offset:320\n\t"
    "global_load_dwordx4 %6, %32, off offset:384\n\t"
    "global_load_dwordx4 %7, %32, off offset:448\n\t"
    "global_load_dwordx4 %8, %33, off\n\t"
    "global_load_dwordx4 %9, %33, off offset:64\n\t"
    "global_load_dwordx4 %10, %33, off offset:128\n\t"
    "global_load_dwordx4 %11, %33, off offset:192\n\t"
    "global_load_dwordx4 %12, %33, off offset:256\n\t"
    "global_load_dwordx4 %13, %33, off offset:320\n\t"
    "global_load_dwordx4 %14, %33, off offset:384\n\t"
    "global_load_dwordx4 %15, %33, off offset:448\n\t"
    "global_load_dwordx4 %16, %34, off\n\t"
    "global_load_dwordx4 %17, %34, off offset:64\n\t"
    "global_load_dwordx4 %18, %34, off offset:128\n\t"
    "global_load_dwordx4 %19, %34, off offset:192\n\t"
    "global_load_dwordx4 %20, %34, off offset:256\n\t"
    "global_load_dwordx4 %21, %34, off offset:320\n\t"
    "global_load_dwordx4 %22, %34, off offset:384\n\t"
    "global_load_dwordx4 %23, %34, off offset:448\n\t"
    "global_load_dwordx4 %24, %35, off\n\t"
    "global_load_dwordx4 %25, %35, off offset:64\n\t"
    "global_load_dwordx4 %26, %35, off offset:128\n\t"
    "global_load_dwordx4 %27, %35, off offset:192\n\t"
    "global_load_dwordx4 %28, %35, off offset:256\n\t"
    "global_load_dwordx4 %29, %35, off offset:320\n\t"
    "global_load_dwordx4 %30, %35, off offset:384\n\t"
    "global_load_dwordx4 %31, %35, off offset:448\n\t"
    "s_waitcnt vmcnt(0)"
    : "=&v"(a[0][0]), "=&v"(a[0][1]), "=&v"(a[0][2]), "=&v"(a[0][3]),
      "=&v"(a[0][4]), "=&v"(a[0][5]), "=&v"(a[0][6]), "=&v"(a[0][7]),
      "=&v"(a[1][0]), "=&v"(a[1][1]), "=&v"(a[1][2]), "=&v"(a[1][3]),
      "=&v"(a[1][4]), "=&v"(a[1][5]), "=&v"(a[1][6]), "=&v"(a[1][7]),
      "=&v"(a[2][0]), "=&v"(a[2][1]), "=&v"(a[2][2]), "=&v"(a[2][3]),
      "=&v"(a[2][4]), "=&v"(a[2][5]), "=&v"(a[2][6]), "=&v"(a[2][7]),
      "=&v"(a[3][0]), "=&v"(a[3][1]), "=&v"(a[3][2]), "=&v"(a[3][3]),
      "=&v"(a[3][4]), "=&v"(a[3][5]), "=&v"(a[3][6]), "=&v"(a[3][7])
    : "v"(p0), "v"(p1), "v"(p2), "v"(p3)
    : "memory");
}

template<int NKB>
__device__ __forceinline__ void mfmaA(const short8 a[4][NKB], const short8 B[4][NKB],
                                      f32x4 acc[4][4]){
  #pragma unroll
  for (int kb = 0; kb < NKB; ++kb)
    #pragma unroll
    for (int m = 0; m < 4; ++m)
      #pragma unroll
      for (int tt = 0; tt < 4; ++tt)
        acc[m][tt] = mfma16(B[tt][kb], a[m][kb], acc[m][tt]);
}

// All-to-all K-partial reduce through LDS. Wave w finalizes batch-tile m==w.
__device__ __forceinline__ void reduceWrite(float* red, int w, int l15, int l4, f32x4 acc[4][4]){
  #pragma unroll
  for (int m = 0; m < 4; ++m){
    if (m == w) continue;
    int mi = (m > w) ? m - 1 : m;
    #pragma unroll
    for (int tt = 0; tt < 4; ++tt){
      float* p = red + (w*12 + mi*4 + tt)*320 + l15*20 + l4*4;
      *(f32x4*)p = acc[m][tt];
    }
  }
}
__device__ __forceinline__ void reduceRead(const float* red, int w, int l15, int l4,
                                           f32x4 gf[4], f32x4 acc[4][4]){
  #pragma unroll
  for (int tt = 0; tt < 4; ++tt) gf[tt] = acc[w][tt];
  #pragma unroll
  for (int v = 0; v < 4; ++v){
    if (v == w) continue;
    int mi = (w > v) ? w - 1 : w;
    #pragma unroll
    for (int tt = 0; tt < 4; ++tt){
      const float* p = red + (v*12 + mi*4 + tt)*320 + l15*20 + l4*4;
      gf[tt] += *(const f32x4*)p;
    }
  }
}

// Gate math + packed 8B agent-coherent h store.
__device__ __forceinline__ void gatesStore(f32x4 gf[4], f32x4& cst,
                                           unsigned short* __restrict__ hdst){
  f32x4 hh;
  #pragma unroll
  for (int r = 0; r < 4; ++r){
    float iv = sigf(gf[0][r]), fv = sigf(gf[1][r]);
    float gv = tanh_(gf[2][r]), ov = sigf(gf[3][r]);
    float cv = fv * cst[r] + iv * gv;
    cst[r] = cv;
    hh[r] = ov * tanh_(cv);
  }
  unsigned long long pk = (unsigned long long)f2bf(hh[0])
    | ((unsigned long long)f2bf(hh[1]) << 16)
    | ((unsigned long long)f2bf(hh[2]) << 32)
    | ((unsigned long long)f2bf(hh[3]) << 48);
  __hip_atomic_store((unsigned long long*)hdst, pk, __ATOMIC_RELAXED, __HIP_MEMORY_SCOPE_AGENT);
}

// ---------------- layer 0 recurrent ----------------
template<int NXB, int NHB>
__device__ void l0_loop(int g, int w, int lane,
                        const unsigned short* __restrict__ Wg,
                        const float* __restrict__ bias0,
                        const unsigned short* __restrict__ xb,
                        unsigned short* __restrict__ h0seq,
                        int* flags0, float* red, int hk0){
  int l15 = lane & 15, l4 = lane >> 4;
  short8 Bx[4][(NXB > 0) ? NXB : 1];
  if constexpr (NXB > 0) loadB<NXB>(Wg, 576, 0, l15, l4, Bx);
  short8 Bh[4][NHB];
  loadB<NHB>(Wg, 576, 64 + hk0, l15, l4, Bh);
  f32x4 bsv[4];
  #pragma unroll
  for (int tt = 0; tt < 4; ++tt) bsv[tt] = *(const f32x4*)&bias0[(g*4 + tt)*16 + l4*4];
  f32x4 cst = {0.f, 0.f, 0.f, 0.f};
  int b = w*16 + l15, colb = g*16 + l4*4;

  for (int t = 0; t < T_STEPS; ++t){
    f32x4 acc[4][4];
    #pragma unroll
    for (int m = 0; m < 4; ++m)
      #pragma unroll
      for (int tt = 0; tt < 4; ++tt) acc[m][tt] = (f32x4){0.f,0.f,0.f,0.f};
    if constexpr (NXB > 0)
      gemmA<NXB>(xb + (long)t*64, (long)T_STEPS*64, l15, l4, Bx, acc);
    if (t){
      spinL0(flags0, t);
      gemmA<NHB>(h0seq + (long)(t-1)*BATCH*HID + hk0, HID, l15, l4, Bh, acc);
    }
    reduceWrite(red, w, l15, l4, acc);
    __syncthreads();
    f32x4 gf[4];
    reduceRead(red, w, l15, l4, gf, acc);
    #pragma unroll
    for (int tt = 0; tt < 4; ++tt) gf[tt] += bsv[tt];
    gatesStore(gf, cst, h0seq + (long)t*BATCH*HID + (long)b*HID + colb);
    __syncthreads();
    if (threadIdx.x == 0) signalSlot(&flags0[g*32], t + 1);
  }
}

// ------- layer 1 (gemm loads forced-batched via asm) -------
__device__ void l1_loop(int g, int w, int lane,
                        const unsigned short* __restrict__ Wg,
                        const float* __restrict__ bias1,
                        const unsigned short* __restrict__ h0seq,
                        unsigned short* __restrict__ h1seq,
                        int* flags0, int* flags1, float* red){
  int l15 = lane & 15, l4 = lane >> 4;
  short8 Bh[4][8];
  loadB<8>(Wg, 1024, w*256, l15, l4, Bh);
  f32x4 bsv[4];
  #pragma unroll
  for (int tt = 0; tt < 4; ++tt) bsv[tt] = *(const f32x4*)&bias1[(g*4 + tt)*16 + l4*4];
  f32x4 cst = {0.f, 0.f, 0.f, 0.f};
  int b = w*16 + l15, colb = g*16 + l4*4;

  for (int t = 0; t < T_STEPS; ++t){
    spinL1(flags0, flags1, t);
    f32x4 acc[4][4];
    #pragma unroll
    for (int m = 0; m < 4; ++m)
      #pragma unroll
      for (int tt = 0; tt < 4; ++tt) acc[m][tt] = (f32x4){0.f,0.f,0.f,0.f};
    if (w < 2){
      short8 ah[4][8];
      loadA8(h0seq + (long)t*BATCH*HID + w*256, HID, l15, l4, ah);
      mfmaA<8>(ah, Bh, acc);
    } else if (t){
      short8 ah[4][8];
      loadA8(h1seq + (long)(t-1)*BATCH*HID + (w-2)*256, HID, l15, l4, ah);
      mfmaA<8>(ah, Bh, acc);
    }
    reduceWrite(red, w, l15, l4, acc);
    __syncthreads();
    f32x4 gf[4];
    reduceRead(red, w, l15, l4, gf, acc);
    #pragma unroll
    for (int tt = 0; tt < 4; ++tt) gf[tt] += bsv[tt];
    gatesStore(gf, cst, h1seq + (long)t*BATCH*HID + (long)b*HID + colb);
    __syncthreads();
    if (threadIdx.x == 0) signalSlot(&flags1[g*32], t + 1);
  }
}

// ---------------- persistent kernel ----------------
extern "C" __global__ void __launch_bounds__(256, 1)
lstm_persist(const unsigned short* __restrict__ Wpk0,
             const unsigned short* __restrict__ Wpk1,
             const float* __restrict__ bias0, const float* __restrict__ bias1,
             const unsigned short* __restrict__ xb,
             unsigned short* __restrict__ h0seq, unsigned short* __restrict__ h1seq,
             int* flags0, int* flags1){
  __shared__ float red[15360];   // 60 KB reduce buffer
  int wg = blockIdx.x;
  int role = wg >> 5;
  int g = wg & 31;
  int w = threadIdx.x >> 6;
  int lane = threadIdx.x & 63;

  if (role == 0){
    const unsigned short* Wg = Wpk0 + (long)g*4*16*576;
    switch (w){
      case 0:  l0_loop<2,3>(g, 0, lane, Wg, bias0, xb, h0seq, flags0, red, 0);   break;
      case 1:  l0_loop<0,5>(g, 1, lane, Wg, bias0, xb, h0seq, flags0, red, 96);  break;
      case 2:  l0_loop<0,4>(g, 2, lane, Wg, bias0, xb, h0seq, flags0, red, 256); break;
      default: l0_loop<0,4>(g, 3, lane, Wg, bias0, xb, h0seq, flags0, red, 384); break;
    }
  } else {
    const unsigned short* Wg = Wpk1 + (long)g*4*16*1024;
    l1_loop(g, w, lane, Wg, bias1, h0seq, h1seq, flags0, flags1, red);
  }
}

// ---------------- prep: repack weights, convert x, zero flags ----------------
extern "C" __global__ void prep_kernel(const float* __restrict__ x,
    const float* __restrict__ Wih0, const float* __restrict__ Whh0,
    const float* __restrict__ bih0, const float* __restrict__ bhh0,
    const float* __restrict__ Wih1, const float* __restrict__ Whh1,
    const float* __restrict__ bih1, const float* __restrict__ bhh1,
    unsigned short* __restrict__ Wpk0, unsigned short* __restrict__ Wpk1,
    float* __restrict__ bias0, float* __restrict__ bias1,
    unsigned short* __restrict__ xb, int* __restrict__ syncm){
  long gid = (long)blockIdx.x * blockDim.x + threadIdx.x;
  long gs  = (long)gridDim.x * blockDim.x;
  const long NW0 = 32L*4*16*576;
  const long NW1 = 32L*4*16*1024;
  const long NX  = 64L*512*64;

  for (long i = gid; i < NW0; i += gs){
    int k = (int)(i % 576);
    long q = i / 576;
    int r  = (int)(q & 15);
    long q2 = q >> 4;
    int tt = (int)(q2 & 3);
    int g  = (int)(q2 >> 2);
    int row = tt*512 + g*16 + r;
    float v = (k < 64) ? Wih0[(long)row*64 + k] : Whh0[(long)row*512 + (k - 64)];
    Wpk0[i] = f2bf(v);
  }
  for (long i = gid; i < NW1; i += gs){
    int k = (int)(i & 1023);
    long q = i >> 10;
    int r  = (int)(q & 15);
    long q2 = q >> 4;
    int tt = (int)(q2 & 3);
    int g  = (int)(q2 >> 2);
    int row = tt*512 + g*16 + r;
    float v = (k < 512) ? Wih1[(long)row*512 + k] : Whh1[(long)row*512 + (k - 512)];
    Wpk1[i] = f2bf(v);
  }
  for (long i = gid; i < 2048; i += gs){
    int r = (int)(i & 15);
    int tt = (int)((i >> 4) & 3);
    int g  = (int)(i >> 6);
    int row = tt*512 + g*16 + r;
    bias0[i] = bih0[row] + bhh0[row];
    bias1[i] = bih1[row] + bhh1[row];
  }
  for (long i = gid; i < NX; i += gs) xb[i] = f2bf(x[i]);
  for (long i = gid; i < 2048; i += gs) syncm[i] = 0;   // flags0[1024] + flags1[1024]
}

// ---------------- head: out[b,t] = h1[t,b,:] . wfc + bfc ----------------
extern "C" __global__ void head_kernel(const unsigned short* __restrict__ h1seq,
    const float* __restrict__ wfc, const float* __restrict__ bfc,
    float* __restrict__ out){
  int t = blockIdx.x;
  int tid = threadIdx.x;
  int b = tid >> 2, q = tid & 3;
  const unsigned short* hp = h1seq + ((long)t*BATCH + b)*HID + q*128;
  const float* wp = wfc + q*128;
  float s = 0.f;
  #pragma unroll
  for (int i = 0; i < 16; ++i){
    short8 v = *(const short8*)(hp + i*8);
    #pragma unroll
    for (int e = 0; e < 8; ++e)
      s += bf2f((unsigned short)v[e]) * wp[i*8 + e];
  }
  s += __shfl_xor(s, 1, 64);
  s += __shfl_xor(s, 2, 64);
  if (q == 0) out[(long)b*T_STEPS + t] = s + bfc[0];
}

extern "C" void kernel_launch(void* const* d_in, const int* in_sizes, int n_in,
                              void* d_out, int out_size, void* d_ws, size_t ws_size,
                              hipStream_t stream){
  const float* x    = (const float*)d_in[0];
  const float* Wih0 = (const float*)d_in[1];
  const float* Whh0 = (const float*)d_in[2];
  const float* bih0 = (const float*)d_in[3];
  const float* bhh0 = (const float*)d_in[4];
  const float* Wih1 = (const float*)d_in[5];
  const float* Whh1 = (const float*)d_in[6];
  const float* bih1 = (const float*)d_in[7];
  const float* bhh1 = (const float*)d_in[8];
  const float* wfc  = (const float*)d_in[9];
  const float* bfc  = (const float*)d_in[10];
  float* out = (float*)d_out;

  char* p = (char*)d_ws;
  auto carve = [&](size_t bytes) -> void* {
    void* r = (void*)p;
    p += (bytes + 255) & ~(size_t)255;
    return r;
  };
  unsigned short* Wpk0  = (unsigned short*)carve(32L*4*16*576*2);
  unsigned short* Wpk1  = (unsigned short*)carve(32L*4*16*1024*2);
  float* bias0 = (float*)carve(2048*4);
  float* bias1 = (float*)carve(2048*4);
  unsigned short* xb    = (unsigned short*)carve(64L*512*64*2);
  unsigned short* h0seq = (unsigned short*)carve(512L*64*512*2);
  unsigned short* h1seq = (unsigned short*)carve(512L*64*512*2);
  int* syncm   = (int*)carve(8192);
  int* flags0 = syncm;           // 32 slots x 32-int stride (128B lines)
  int* flags1 = syncm + 1024;

  hipLaunchKernelGGL(prep_kernel, dim3(1024), dim3(256), 0, stream,
                     x, Wih0, Whh0, bih0, bhh0, Wih1, Whh1, bih1, bhh1,
                     Wpk0, Wpk1, bias0, bias1, xb, syncm);
  hipLaunchKernelGGL(lstm_persist, dim3(64), dim3(256), 0, stream,
                     Wpk0, Wpk1, bias0, bias1, xb, h0seq, h1seq, flags0, flags1);
  hipLaunchKernelGGL(head_kernel, dim3(512), dim3(256), 0, stream,
                     h1seq, wfc, bfc, out);
}